// Round 9
// baseline (239.013 us; speedup 1.0000x reference)
//
#include <hip/hip_runtime.h>
#include <hip/hip_bf16.h>
#include <stdint.h>

typedef unsigned short ushort_t;

#define BB 8
#define SS 1024
#define TT 1024
#define DD 1024
#define INF_ 1e10f

__device__ __forceinline__ float b2f(ushort_t u){
  union { unsigned u32; float f; } x; x.u32 = ((unsigned)u) << 16; return x.f;
}
__device__ __forceinline__ ushort_t f2b(float f){
  union { float f; unsigned u; } x; x.f = f;
  unsigned r = x.u + 0x7FFFu + ((x.u >> 16) & 1u);
  return (ushort_t)(r >> 16);
}

// ------- steps = sum(mask_src)/sum(mask_trg) per batch; also zero-inits v2 -------
__global__ __launch_bounds__(256) void steps_kernel(
    const float* __restrict__ msrc, const float* __restrict__ mtrg,
    float* __restrict__ steps, float* __restrict__ v2)
{
  __shared__ float sh[8];
  int b = blockIdx.x, tid = threadIdx.x;
  if (b < 4) v2[b*256 + tid] = 0.f;       // zero v2 (1024 floats) for atomic accum
  float a = 0.f, c = 0.f;
  for (int i = tid; i < SS; i += 256) a += msrc[b*SS + i];
  for (int i = tid; i < TT; i += 256) c += mtrg[b*TT + i];
  #pragma unroll
  for (int o = 32; o; o >>= 1){ a += __shfl_xor(a, o); c += __shfl_xor(c, o); }
  int wv = tid >> 6, ln = tid & 63;
  if (!ln){ sh[wv] = a; sh[4+wv] = c; }
  __syncthreads();
  if (!tid){
    float sa = sh[0]+sh[1]+sh[2]+sh[3];
    float sc = sh[4]+sh[5]+sh[6]+sh[7];
    steps[b] = sa / sc;
  }
}

// ---------------- v2[f] = sum_d Wk[d,f] * bq[d]  (coalesced, 32 row-blocks) ----------------
__global__ __launch_bounds__(256) void v2_kernel(
    const float* __restrict__ Wk, const float* __restrict__ bq,
    float* __restrict__ v2)
{
  int tid = threadIdx.x;
  int f = tid * 4;
  int r0 = blockIdx.x * 32;
  float a0=0.f, a1=0.f, a2=0.f, a3=0.f;
  for (int r = 0; r < 32; r++){
    float s = bq[r0 + r];
    float4 w = *(const float4*)(Wk + (size_t)(r0 + r)*DD + f);
    a0 += s*w.x; a1 += s*w.y; a2 += s*w.z; a3 += s*w.w;
  }
  atomicAdd(&v2[f+0], a0); atomicAdd(&v2[f+1], a1);
  atomicAdd(&v2[f+2], a2); atomicAdd(&v2[f+3], a3);
}

// ------- key row convert fp32->bf16, plus kw = key·wg, cv = key·v2 per row -------
__global__ __launch_bounds__(256) void key_convert_kernel(
    const float* __restrict__ key, const float* __restrict__ wg,
    const float* __restrict__ v2f, ushort_t* __restrict__ keyb,
    float* __restrict__ kw, float* __restrict__ cv)
{
  __shared__ float sh[8];
  int row = blockIdx.x;       // b*SS + s
  int tid = threadIdx.x, d0 = tid*4;
  float4 v = *(const float4*)(key + (size_t)row*DD + d0);
  ushort4 o; o.x=f2b(v.x); o.y=f2b(v.y); o.z=f2b(v.z); o.w=f2b(v.w);
  *(ushort4*)(keyb + (size_t)row*DD + d0) = o;
  float4 w4 = *(const float4*)(wg + d0);
  float4 u4 = *(const float4*)(v2f + d0);
  float pk = v.x*w4.x + v.y*w4.y + v.z*w4.z + v.w*w4.w;
  float pc = v.x*u4.x + v.y*u4.y + v.z*u4.z + v.w*u4.w;
  #pragma unroll
  for (int off = 32; off; off >>= 1){ pk += __shfl_xor(pk, off); pc += __shfl_xor(pc, off); }
  int wvv = tid >> 6;
  if ((tid & 63) == 0){ sh[wvv] = pk; sh[4+wvv] = pc; }
  __syncthreads();
  if (!tid){
    kw[row] = sh[0]+sh[1]+sh[2]+sh[3];
    cv[row] = sh[4]+sh[5]+sh[6]+sh[7];
  }
}

// ----- transpose + convert both W matrices: dst[e,d] = bf16(src[d,e]), z selects Wq/Wk -----
__global__ __launch_bounds__(256) void transpose_convert_kernel(
    const float* __restrict__ Wq, const float* __restrict__ Wk,
    ushort_t* __restrict__ WqT, ushort_t* __restrict__ WkT)
{
  __shared__ float tile[32][33];
  const float* src = blockIdx.z ? Wk : Wq;
  ushort_t* dst = blockIdx.z ? WkT : WqT;
  int tx = blockIdx.x, ty = blockIdx.y;
  int tid = threadIdx.x;
  int c = tid & 31, r0 = tid >> 5;
  #pragma unroll
  for (int k = 0; k < 4; k++){
    int r = r0 + k*8;
    tile[r][c] = src[(size_t)(ty*32 + r)*DD + tx*32 + c];
  }
  __syncthreads();
  #pragma unroll
  for (int k = 0; k < 4; k++){
    int r = r0 + k*8;
    dst[(size_t)(tx*32 + r)*DD + ty*32 + c] = f2b(tile[c][r]);
  }
}

// ---- m97-style bf16 GEMM (global_load_lds width=16): C[M,N] = A[M,K]*B[N,K]^T ----
// Natural 3D grid (R8 post-mortem: manual XCD chunk-swizzle REGRESSED ~9 us;
// workgroup->XCD mapping is undefined on this runtime — do not assume blockIdx%8).
typedef __bf16 bf16x8 __attribute__((ext_vector_type(8)));
typedef float f32x4 __attribute__((ext_vector_type(4)));

#define CP16(g, l) __builtin_amdgcn_global_load_lds( \
    (const __attribute__((address_space(1))) void*)(g), \
    (__attribute__((address_space(3))) void*)(l), 16, 0, 0)

__global__ __launch_bounds__(256, 2) void gemm_bt_kernel(
    const ushort_t* __restrict__ A, const ushort_t* __restrict__ Bm,
    const float* __restrict__ bias, void* __restrict__ Cv,
    int M, int N, int K, int lda, int ldb,
    long long sA, long long sB, long long sC, int hasBias, int outBF16)
{
  __shared__ ushort_t lA[128*32];
  __shared__ ushort_t lB[128*32];
  A  += (size_t)blockIdx.z * sA;
  Bm += (size_t)blockIdx.z * sB;

  const int tid = threadIdx.x;
  const int wv = tid >> 6, ln = tid & 63;
  const int r4 = ln >> 2, c8 = (ln & 3) * 8;

  const ushort_t* gA0 = A  + (size_t)(blockIdx.y*128 + wv*32 + r4) * lda + c8;
  const ushort_t* gA1 = gA0 + (size_t)16 * lda;
  const ushort_t* gB0 = Bm + (size_t)(blockIdx.x*128 + wv*32 + r4) * ldb + c8;
  const ushort_t* gB1 = gB0 + (size_t)16 * ldb;
  ushort_t* lA0 = &lA[(wv*32     ) * 32];
  ushort_t* lA1 = &lA[(wv*32 + 16) * 32];
  ushort_t* lB0 = &lB[(wv*32     ) * 32];
  ushort_t* lB1 = &lB[(wv*32 + 16) * 32];

  const int lm = ln & 15, qd = ln >> 4;
  const int wm = (wv >> 1) * 64, wn = (wv & 1) * 64;

  f32x4 acc[4][4];
  #pragma unroll
  for (int i = 0; i < 4; i++)
    #pragma unroll
    for (int j = 0; j < 4; j++) acc[i][j] = (f32x4){0.f, 0.f, 0.f, 0.f};

  for (int k0 = 0; k0 < K; k0 += 32){
    CP16(gA0, lA0); CP16(gA1, lA1); CP16(gB0, lB0); CP16(gB1, lB1);
    gA0 += 32; gA1 += 32; gB0 += 32; gB1 += 32;
    __syncthreads();
    bf16x8 af[4], bf[4];
    #pragma unroll
    for (int i = 0; i < 4; i++) af[i] = *(const bf16x8*)&lA[(wm + i*16 + lm)*32 + qd*8];
    #pragma unroll
    for (int j = 0; j < 4; j++) bf[j] = *(const bf16x8*)&lB[(wn + j*16 + lm)*32 + qd*8];
    #pragma unroll
    for (int i = 0; i < 4; i++)
      #pragma unroll
      for (int j = 0; j < 4; j++)
        acc[i][j] = __builtin_amdgcn_mfma_f32_16x16x32_bf16(af[i], bf[j], acc[i][j], 0, 0, 0);
    __syncthreads();
  }

  // C/D layout: col = lane&15, row = (lane>>4)*4 + reg   [verified m89/m91]
  const int row0 = blockIdx.y*128 + wm + qd*4;
  const int col0 = blockIdx.x*128 + wn + lm;
  ushort_t* Cb = (ushort_t*)Cv + (size_t)blockIdx.z * sC;
  float*    Cf = (float*)Cv    + (size_t)blockIdx.z * sC;
  #pragma unroll
  for (int j = 0; j < 4; j++){
    int col = col0 + j*16;
    float bv = hasBias ? bias[col] : 0.f;
    #pragma unroll
    for (int i = 0; i < 4; i++)
      #pragma unroll
      for (int r = 0; r < 4; r++){
        size_t idx = (size_t)(row0 + i*16 + r) * N + col;
        float v = acc[i][j][r] + bv;
        if (outBF16) Cb[idx] = f2b(v); else Cf[idx] = v;
      }
  }
}

// ---------------- sum 4 split-K fp32 partials -> bf16 ----------------
__global__ __launch_bounds__(256) void wmt_reduce_kernel(
    const float* __restrict__ part, ushort_t* __restrict__ dst)
{
  int i4 = blockIdx.x * 256 + threadIdx.x;   // float4 index, n = 1024*1024/4
  const float4* p = (const float4*)part;
  float4 a = p[i4];
  float4 b = p[i4 + 262144];
  float4 c = p[i4 + 524288];
  float4 d = p[i4 + 786432];
  ushort4 o;
  o.x = f2b(a.x + b.x + c.x + d.x);
  o.y = f2b(a.y + b.y + c.y + d.y);
  o.z = f2b(a.z + b.z + c.z + d.z);
  o.w = f2b(a.w + b.w + c.w + d.w);
  ((ushort4*)dst)[i4] = o;
}

// ----- banded l_att stencil on km: qm2[t] = sum_s w[t,s]*km[b,s]; gates from kw -----
// 16 t's per block; union band (~33 rows) read once.
__global__ __launch_bounds__(256) void band_kernel(
    const ushort_t* __restrict__ kmb, const float* __restrict__ mask_src,
    const float* __restrict__ steps, const float* __restrict__ kw,
    const float* __restrict__ bg, ushort_t* __restrict__ qm2b,
    float* __restrict__ gates)
{
  __shared__ float shw[16][17];
  __shared__ int shslo[16];
  int bx = blockIdx.x;
  int b = bx >> 6, t0 = (bx & 63) * 16;
  int tid = threadIdx.x;

  if (tid < 16){
    int t = t0 + tid;
    float c = steps[b] * (float)t;
    int slo = (int)ceilf(c - 8.0f);
    float w[17], m = -3e38f;
    #pragma unroll
    for (int i = 0; i < 17; i++){
      int s = slo + i;
      float l = -3e38f;
      if (s >= 0 && s < SS){
        float dd = (float)s - c;
        l = -dd*dd*(1.0f/0.3f) - INF_*(1.0f - mask_src[b*SS + s]);
      }
      w[i] = l; m = fmaxf(m, l);
    }
    float norm = 0.f, ga = 0.f;
    #pragma unroll
    for (int i = 0; i < 17; i++){
      float e = __expf(w[i] - m);
      int s = slo + i;
      if (s >= 0 && s < SS) ga += e * kw[b*SS + s]; else e = 0.f;
      w[i] = e; norm += e;
    }
    float inv = 1.0f / norm;
    #pragma unroll
    for (int i = 0; i < 17; i++) shw[tid][i] = w[i] * inv;
    shslo[tid] = slo;
    gates[b*TT + t] = 1.0f / (1.0f + __expf(-(ga*inv + bg[0])));
  }
  __syncthreads();

  int smin = shslo[0], smax = shslo[15] + 16;
  if (smin < 0) smin = 0;
  if (smax > SS-1) smax = SS-1;
  int d0 = tid * 4;
  float acc[16][4];
  #pragma unroll
  for (int t = 0; t < 16; t++){ acc[t][0]=0.f; acc[t][1]=0.f; acc[t][2]=0.f; acc[t][3]=0.f; }

  const ushort_t* kbase = kmb + ((size_t)b*SS)*DD + d0;
  for (int s = smin; s <= smax; s++){
    ushort4 kv = *(const ushort4*)(kbase + (size_t)s*DD);
    float k0 = b2f(kv.x), k1 = b2f(kv.y), k2 = b2f(kv.z), k3 = b2f(kv.w);
    #pragma unroll
    for (int t = 0; t < 16; t++){
      unsigned u = (unsigned)(s - shslo[t]);
      if (u < 17u){
        float wgt = shw[t][u];
        acc[t][0] += wgt*k0; acc[t][1] += wgt*k1; acc[t][2] += wgt*k2; acc[t][3] += wgt*k3;
      }
    }
  }
  #pragma unroll
  for (int t = 0; t < 16; t++){
    ushort4 o; o.x=f2b(acc[t][0]); o.y=f2b(acc[t][1]); o.z=f2b(acc[t][2]); o.w=f2b(acc[t][3]);
    *(ushort4*)(qm2b + ((size_t)(b*TT + t0 + t))*DD + d0) = o;
  }
}

// ------- fused softmax((dots_bf16+cv)/scale) + exact l_att + gated mix -> fp32 out -------
__device__ __forceinline__ float blkmax(float v, float* sh){
  #pragma unroll
  for (int o = 32; o; o >>= 1) v = fmaxf(v, __shfl_xor(v, o));
  __syncthreads();
  if ((threadIdx.x & 63) == 0) sh[threadIdx.x >> 6] = v;
  __syncthreads();
  return fmaxf(fmaxf(sh[0], sh[1]), fmaxf(sh[2], sh[3]));
}
__device__ __forceinline__ float blksum(float v, float* sh){
  #pragma unroll
  for (int o = 32; o; o >>= 1) v += __shfl_xor(v, o);
  __syncthreads();
  if ((threadIdx.x & 63) == 0) sh[threadIdx.x >> 6] = v;
  __syncthreads();
  return sh[0] + sh[1] + sh[2] + sh[3];
}

__global__ __launch_bounds__(256) void softmax_mix_kernel(
    const ushort_t* __restrict__ dotsb, float* __restrict__ out,
    const float* __restrict__ mask_src, const float* __restrict__ steps,
    const float* __restrict__ gates, const float* __restrict__ cv)
{
  __shared__ float sh[4];
  int blk = blockIdx.x;
  int b = blk >> 10, t = blk & 1023;
  int tid = threadIdx.x;
  int s0 = tid * 4;
  float c = steps[b] * (float)t;

  ushort4 dv = *(const ushort4*)(dotsb + (size_t)blk*SS + s0);
  float4 mv = *(const float4*)(mask_src + (size_t)b*SS + s0);
  float4 cva = *(const float4*)(cv + (size_t)b*SS + s0);
  float dvf[4] = {b2f(dv.x) + cva.x, b2f(dv.y) + cva.y, b2f(dv.z) + cva.z, b2f(dv.w) + cva.w};
  float msk[4] = {mv.x, mv.y, mv.z, mv.w};
  float dl[4], ll[4];
  float dmax = -3e38f, lmax = -3e38f;
  #pragma unroll
  for (int r = 0; r < 4; r++){
    float im = INF_ * (1.0f - msk[r]);
    dl[r] = (dvf[r] - im) * (1.0f/32.0f);          // scale = sqrt(1024) = 32
    float dd = (float)(s0 + r) - c;
    ll[r] = -dd*dd*(1.0f/0.3f) - im;
    dmax = fmaxf(dmax, dl[r]);
    lmax = fmaxf(lmax, ll[r]);
  }
  float dm = blkmax(dmax, sh);    // contains barriers: all dotsb reads complete
  float ps[4], lp[4];
  float psum = 0.f, lsum = 0.f;
  #pragma unroll
  for (int r = 0; r < 4; r++){ ps[r] = __expf(dl[r] - dm); psum += ps[r]; }
  psum = blksum(psum, sh);
  float lm2 = blkmax(lmax, sh);
  #pragma unroll
  for (int r = 0; r < 4; r++){ lp[r] = __expf(ll[r] - lm2); lsum += lp[r]; }
  lsum = blksum(lsum, sh);

  float g = gates[blk];
  float ip = (1.0f - g) / psum, il = g / lsum;
  float4 ov;
  ov.x = ps[0]*ip + lp[0]*il;
  ov.y = ps[1]*ip + lp[1]*il;
  ov.z = ps[2]*ip + lp[2]*il;
  ov.w = ps[3]*ip + lp[3]*il;
  *(float4*)(out + (size_t)blk*SS + s0) = ov;
}

extern "C" void kernel_launch(void* const* d_in, const int* in_sizes, int n_in,
                              void* d_out, int out_size, void* d_ws, size_t ws_size,
                              hipStream_t stream)
{
  const float* key      = (const float*)d_in[0];
  const float* mask_src = (const float*)d_in[1];
  const float* mask_trg = (const float*)d_in[2];
  const float* Wq       = (const float*)d_in[3];
  const float* bq       = (const float*)d_in[4];
  const float* Wk       = (const float*)d_in[5];
  const float* bk       = (const float*)d_in[6];
  const float* wg       = (const float*)d_in[7];
  const float* bg       = (const float*)d_in[8];
  float* out = (float*)d_out;   // fp32 [B,T,S] = 32 MB
  (void)bk;  // bk contributes only row-constant softmax shift -> cancels

  // dots (bf16, 16 MB) lives in the UPPER half of d_out until softmax consumes it
  ushort_t* dotsb = (ushort_t*)(out + (size_t)4*1024*1024);

  // ws layout (~54.3 MB):
  char* ws = (char*)d_ws;
  float* steps     = (float*)ws;                         // 32 B
  float* gates     = (float*)(ws + 4096);                // 32 KB
  float* cv        = (float*)(ws + 4096 + 32768);        // 32 KB
  float* kw        = (float*)(ws + 4096 + 65536);        // 32 KB
  float* v2        = (float*)(ws + 4096 + 98304);        // 4 KB
  ushort_t* WqTb   = (ushort_t*)(ws + 131072);           // 2 MB
  ushort_t* WkTb   = WqTb + (size_t)DD*DD;               // 2 MB
  ushort_t* WmTb   = WkTb + (size_t)DD*DD;               // 2 MB
  ushort_t* keyb   = WmTb + (size_t)DD*DD;               // 16 MB
  ushort_t* kmb    = keyb + (size_t)BB*SS*DD;            // 16 MB
  char* shared16   = (char*)(kmb + (size_t)BB*SS*DD);    // 16 MB: WmT partials, later qm2b
  float* wmPart    = (float*)shared16;                   // 4 x 1M fp32
  ushort_t* qm2b   = (ushort_t*)shared16;                // 16 MB (after wmt_reduce)

  steps_kernel<<<BB, 256, 0, stream>>>(mask_src, mask_trg, steps, v2);
  v2_kernel<<<32, 256, 0, stream>>>(Wk, bq, v2);
  key_convert_kernel<<<BB*SS, 256, 0, stream>>>(key, wg, v2, keyb, kw, cv);
  transpose_convert_kernel<<<dim3(32,32,2), 256, 0, stream>>>(Wq, Wk, WqTb, WkTb);
  // WmT[f,e] = sum_d Wk[d,f] Wq[d,e] = WkT @ WqT^T, split-K=4 over d
  gemm_bt_kernel<<<dim3(8,8,4), 256, 0, stream>>>(
      WkTb, WqTb, nullptr, (void*)wmPart, DD, DD, DD/4, DD, DD,
      DD/4, DD/4, (long long)DD*DD, 0, 0);
  wmt_reduce_kernel<<<DD*DD/4/256, 256, 0, stream>>>(wmPart, WmTb);
  // km = keyb @ Wm = gemm_bt(keyb, WmT)  [8192 x 1024 x 1024] -> bf16
  gemm_bt_kernel<<<dim3(8,64,1), 256, 0, stream>>>(
      keyb, WmTb, nullptr, (void*)kmb, BB*SS, DD, DD, DD, DD, 0, 0, 0, 0, 1);
  // qm2 = l_att · km (banded) + gates
  band_kernel<<<BB*TT/16, 256, 0, stream>>>(kmb, mask_src, steps, kw, bg, qm2b, gates);
  // dots[b] = qm2[b] @ keyb[b]^T -> dotsb (bf16, upper half of out)
  gemm_bt_kernel<<<dim3(8,8,8), 256, 0, stream>>>(
      qm2b, keyb, nullptr, (void*)dotsb, TT, SS, DD, DD, DD,
      (long long)TT*DD, (long long)SS*DD, (long long)TT*SS, 0, 1);
  softmax_mix_kernel<<<BB*TT, 256, 0, stream>>>(dotsb, out, mask_src, steps, gates, cv);
}

// Round 10
// 217.123 us; speedup vs baseline: 1.1008x; 1.1008x over previous
//
#include <hip/hip_runtime.h>
#include <hip/hip_bf16.h>
#include <stdint.h>

typedef unsigned short ushort_t;

#define BB 8
#define SS 1024
#define TT 1024
#define DD 1024
#define INF_ 1e10f

__device__ __forceinline__ float b2f(ushort_t u){
  union { unsigned u32; float f; } x; x.u32 = ((unsigned)u) << 16; return x.f;
}
__device__ __forceinline__ ushort_t f2b(float f){
  union { float f; unsigned u; } x; x.f = f;
  unsigned r = x.u + 0x7FFFu + ((x.u >> 16) & 1u);
  return (ushort_t)(r >> 16);
}

// ---- preamble: blocks 0..2047 transpose Wq/Wk -> bf16; 2048..2055 steps (+v2 zero) ----
__global__ __launch_bounds__(256) void pre_kernel(
    const float* __restrict__ Wq, const float* __restrict__ Wk,
    ushort_t* __restrict__ WqT, ushort_t* __restrict__ WkT,
    const float* __restrict__ msrc, const float* __restrict__ mtrg,
    float* __restrict__ steps, float* __restrict__ v2)
{
  __shared__ float tile[32][33];
  __shared__ float sh[8];
  int blk = blockIdx.x, tid = threadIdx.x;
  if (blk < 2048){
    const float* src = (blk >= 1024) ? Wk : Wq;
    ushort_t* dst = (blk >= 1024) ? WkT : WqT;
    int q = blk & 1023;
    int tx = q & 31, ty = q >> 5;
    int c = tid & 31, r0 = tid >> 5;
    #pragma unroll
    for (int k = 0; k < 4; k++){
      int r = r0 + k*8;
      tile[r][c] = src[(size_t)(ty*32 + r)*DD + tx*32 + c];
    }
    __syncthreads();
    #pragma unroll
    for (int k = 0; k < 4; k++){
      int r = r0 + k*8;
      dst[(size_t)(tx*32 + r)*DD + ty*32 + c] = f2b(tile[c][r]);
    }
  } else {
    int b = blk - 2048;
    if (b < 4) v2[b*256 + tid] = 0.f;      // zero v2 for v2_kernel's atomics
    float a = 0.f, c = 0.f;
    for (int i = tid; i < SS; i += 256) a += msrc[b*SS + i];
    for (int i = tid; i < TT; i += 256) c += mtrg[b*TT + i];
    #pragma unroll
    for (int o = 32; o; o >>= 1){ a += __shfl_xor(a, o); c += __shfl_xor(c, o); }
    int wv = tid >> 6, ln = tid & 63;
    if (!ln){ sh[wv] = a; sh[4+wv] = c; }
    __syncthreads();
    if (!tid){
      float sa = sh[0]+sh[1]+sh[2]+sh[3];
      float sc = sh[4]+sh[5]+sh[6]+sh[7];
      steps[b] = sa / sc;
    }
  }
}

// ---------------- v2[f] = sum_d Wk[d,f] * bq[d]  (coalesced, 32 row-blocks) ----------------
__global__ __launch_bounds__(256) void v2_kernel(
    const float* __restrict__ Wk, const float* __restrict__ bq,
    float* __restrict__ v2)
{
  int tid = threadIdx.x;
  int f = tid * 4;
  int r0 = blockIdx.x * 32;
  float a0=0.f, a1=0.f, a2=0.f, a3=0.f;
  for (int r = 0; r < 32; r++){
    float s = bq[r0 + r];
    float4 w = *(const float4*)(Wk + (size_t)(r0 + r)*DD + f);
    a0 += s*w.x; a1 += s*w.y; a2 += s*w.z; a3 += s*w.w;
  }
  atomicAdd(&v2[f+0], a0); atomicAdd(&v2[f+1], a1);
  atomicAdd(&v2[f+2], a2); atomicAdd(&v2[f+3], a3);
}

// ------- key row convert fp32->bf16, plus kw = key·wg, cv = key·v2 per row -------
__global__ __launch_bounds__(256) void key_convert_kernel(
    const float* __restrict__ key, const float* __restrict__ wg,
    const float* __restrict__ v2f, ushort_t* __restrict__ keyb,
    float* __restrict__ kw, float* __restrict__ cv)
{
  __shared__ float sh[8];
  int row = blockIdx.x;       // b*SS + s
  int tid = threadIdx.x, d0 = tid*4;
  float4 v = *(const float4*)(key + (size_t)row*DD + d0);
  ushort4 o; o.x=f2b(v.x); o.y=f2b(v.y); o.z=f2b(v.z); o.w=f2b(v.w);
  *(ushort4*)(keyb + (size_t)row*DD + d0) = o;
  float4 w4 = *(const float4*)(wg + d0);
  float4 u4 = *(const float4*)(v2f + d0);
  float pk = v.x*w4.x + v.y*w4.y + v.z*w4.z + v.w*w4.w;
  float pc = v.x*u4.x + v.y*u4.y + v.z*u4.z + v.w*u4.w;
  #pragma unroll
  for (int off = 32; off; off >>= 1){ pk += __shfl_xor(pk, off); pc += __shfl_xor(pc, off); }
  int wvv = tid >> 6;
  if ((tid & 63) == 0){ sh[wvv] = pk; sh[4+wvv] = pc; }
  __syncthreads();
  if (!tid){
    kw[row] = sh[0]+sh[1]+sh[2]+sh[3];
    cv[row] = sh[4]+sh[5]+sh[6]+sh[7];
  }
}

// ---- m97-style bf16 GEMM (global_load_lds width=16), 1D grid + XCD chunk map
// (config of the measured-best R8 run) : C[M,N] = A[M,K]*B[N,K]^T ----
typedef __bf16 bf16x8 __attribute__((ext_vector_type(8)));
typedef float f32x4 __attribute__((ext_vector_type(4)));

#define CP16(g, l) __builtin_amdgcn_global_load_lds( \
    (const __attribute__((address_space(1))) void*)(g), \
    (__attribute__((address_space(3))) void*)(l), 16, 0, 0)

__global__ __launch_bounds__(256, 2) void gemm_bt_kernel(
    const ushort_t* __restrict__ A, const ushort_t* __restrict__ Bm,
    const float* __restrict__ bias, void* __restrict__ Cv,
    int M, int N, int K, int lda, int ldb,
    long long sA, long long sB, long long sC, int hasBias, int outBF16,
    int gx, int gxy)
{
  __shared__ ushort_t lA[128*32];
  __shared__ ushort_t lB[128*32];

  const int bpx = gridDim.x >> 3;
  const int lin = blockIdx.x;
  const int glob = (lin & 7) * bpx + (lin >> 3);
  const int bz = glob / gxy;
  const int rem = glob - bz * gxy;
  const int by = rem / gx;
  const int bx = rem - by * gx;

  A  += (size_t)bz * sA;
  Bm += (size_t)bz * sB;

  const int tid = threadIdx.x;
  const int wv = tid >> 6, ln = tid & 63;
  const int r4 = ln >> 2, c8 = (ln & 3) * 8;

  const ushort_t* gA0 = A  + (size_t)(by*128 + wv*32 + r4) * lda + c8;
  const ushort_t* gA1 = gA0 + (size_t)16 * lda;
  const ushort_t* gB0 = Bm + (size_t)(bx*128 + wv*32 + r4) * ldb + c8;
  const ushort_t* gB1 = gB0 + (size_t)16 * ldb;
  ushort_t* lA0 = &lA[(wv*32     ) * 32];
  ushort_t* lA1 = &lA[(wv*32 + 16) * 32];
  ushort_t* lB0 = &lB[(wv*32     ) * 32];
  ushort_t* lB1 = &lB[(wv*32 + 16) * 32];

  const int lm = ln & 15, qd = ln >> 4;
  const int wm = (wv >> 1) * 64, wn = (wv & 1) * 64;

  f32x4 acc[4][4];
  #pragma unroll
  for (int i = 0; i < 4; i++)
    #pragma unroll
    for (int j = 0; j < 4; j++) acc[i][j] = (f32x4){0.f, 0.f, 0.f, 0.f};

  for (int k0 = 0; k0 < K; k0 += 32){
    CP16(gA0, lA0); CP16(gA1, lA1); CP16(gB0, lB0); CP16(gB1, lB1);
    gA0 += 32; gA1 += 32; gB0 += 32; gB1 += 32;
    __syncthreads();
    bf16x8 af[4], bf[4];
    #pragma unroll
    for (int i = 0; i < 4; i++) af[i] = *(const bf16x8*)&lA[(wm + i*16 + lm)*32 + qd*8];
    #pragma unroll
    for (int j = 0; j < 4; j++) bf[j] = *(const bf16x8*)&lB[(wn + j*16 + lm)*32 + qd*8];
    #pragma unroll
    for (int i = 0; i < 4; i++)
      #pragma unroll
      for (int j = 0; j < 4; j++)
        acc[i][j] = __builtin_amdgcn_mfma_f32_16x16x32_bf16(af[i], bf[j], acc[i][j], 0, 0, 0);
    __syncthreads();
  }

  // C/D layout: col = lane&15, row = (lane>>4)*4 + reg   [verified m89/m91]
  const int row0 = by*128 + wm + qd*4;
  const int col0 = bx*128 + wn + lm;
  ushort_t* Cb = (ushort_t*)Cv + (size_t)bz * sC;
  float*    Cf = (float*)Cv    + (size_t)bz * sC;
  #pragma unroll
  for (int j = 0; j < 4; j++){
    int col = col0 + j*16;
    float bv = hasBias ? bias[col] : 0.f;
    #pragma unroll
    for (int i = 0; i < 4; i++)
      #pragma unroll
      for (int r = 0; r < 4; r++){
        size_t idx = (size_t)(row0 + i*16 + r) * N + col;
        float v = acc[i][j][r] + bv;
        if (outBF16) Cb[idx] = f2b(v); else Cf[idx] = v;
      }
  }
}

// ---------------- sum 4 split-K fp32 partials -> bf16 ----------------
__global__ __launch_bounds__(256) void wmt_reduce_kernel(
    const float* __restrict__ part, ushort_t* __restrict__ dst)
{
  int i4 = blockIdx.x * 256 + threadIdx.x;   // float4 index, n = 1024*1024/4
  const float4* p = (const float4*)part;
  float4 a = p[i4];
  float4 b = p[i4 + 262144];
  float4 c = p[i4 + 524288];
  float4 d = p[i4 + 786432];
  ushort4 o;
  o.x = f2b(a.x + b.x + c.x + d.x);
  o.y = f2b(a.y + b.y + c.y + d.y);
  o.z = f2b(a.z + b.z + c.z + d.z);
  o.w = f2b(a.w + b.w + c.w + d.w);
  ((ushort4*)dst)[i4] = o;
}

// ----- banded l_att stencil on km: qm2[t] = sum_s w[t,s]*km[b,s]; gates from kw -----
// 8 t's per block (R9 post-mortem: 16 t/block spilled VGPRs and cost +17 us).
__global__ __launch_bounds__(256) void band_kernel(
    const ushort_t* __restrict__ kmb, const float* __restrict__ mask_src,
    const float* __restrict__ steps, const float* __restrict__ kw,
    const float* __restrict__ bg, ushort_t* __restrict__ qm2b,
    float* __restrict__ gates)
{
  __shared__ float shw[8][17];
  __shared__ int shslo[8];
  int bx = blockIdx.x;
  int b = bx >> 7, t0 = (bx & 127) * 8;
  int tid = threadIdx.x;

  if (tid < 8){
    int t = t0 + tid;
    float c = steps[b] * (float)t;
    int slo = (int)ceilf(c - 8.0f);
    float w[17], m = -3e38f;
    #pragma unroll
    for (int i = 0; i < 17; i++){
      int s = slo + i;
      float l = -3e38f;
      if (s >= 0 && s < SS){
        float dd = (float)s - c;
        l = -dd*dd*(1.0f/0.3f) - INF_*(1.0f - mask_src[b*SS + s]);
      }
      w[i] = l; m = fmaxf(m, l);
    }
    float norm = 0.f, ga = 0.f;
    #pragma unroll
    for (int i = 0; i < 17; i++){
      float e = __expf(w[i] - m);
      int s = slo + i;
      if (s >= 0 && s < SS) ga += e * kw[b*SS + s]; else e = 0.f;
      w[i] = e; norm += e;
    }
    float inv = 1.0f / norm;
    #pragma unroll
    for (int i = 0; i < 17; i++) shw[tid][i] = w[i] * inv;
    shslo[tid] = slo;
    gates[b*TT + t] = 1.0f / (1.0f + __expf(-(ga*inv + bg[0])));
  }
  __syncthreads();

  int smin = shslo[0], smax = shslo[7] + 16;
  if (smin < 0) smin = 0;
  if (smax > SS-1) smax = SS-1;
  int d0 = tid * 4;
  float acc[8][4];
  #pragma unroll
  for (int t = 0; t < 8; t++){ acc[t][0]=0.f; acc[t][1]=0.f; acc[t][2]=0.f; acc[t][3]=0.f; }

  const ushort_t* kbase = kmb + ((size_t)b*SS)*DD + d0;
  for (int s = smin; s <= smax; s++){
    ushort4 kv = *(const ushort4*)(kbase + (size_t)s*DD);
    float k0 = b2f(kv.x), k1 = b2f(kv.y), k2 = b2f(kv.z), k3 = b2f(kv.w);
    #pragma unroll
    for (int t = 0; t < 8; t++){
      unsigned u = (unsigned)(s - shslo[t]);
      if (u < 17u){
        float wgt = shw[t][u];
        acc[t][0] += wgt*k0; acc[t][1] += wgt*k1; acc[t][2] += wgt*k2; acc[t][3] += wgt*k3;
      }
    }
  }
  #pragma unroll
  for (int t = 0; t < 8; t++){
    ushort4 o; o.x=f2b(acc[t][0]); o.y=f2b(acc[t][1]); o.z=f2b(acc[t][2]); o.w=f2b(acc[t][3]);
    *(ushort4*)(qm2b + ((size_t)(b*TT + t0 + t))*DD + d0) = o;
  }
}

// ------- fused softmax((dots_bf16+cv)/scale) + exact l_att + gated mix -> fp32 out -------
__device__ __forceinline__ float blkmax(float v, float* sh){
  #pragma unroll
  for (int o = 32; o; o >>= 1) v = fmaxf(v, __shfl_xor(v, o));
  __syncthreads();
  if ((threadIdx.x & 63) == 0) sh[threadIdx.x >> 6] = v;
  __syncthreads();
  return fmaxf(fmaxf(sh[0], sh[1]), fmaxf(sh[2], sh[3]));
}
__device__ __forceinline__ float blksum(float v, float* sh){
  #pragma unroll
  for (int o = 32; o; o >>= 1) v += __shfl_xor(v, o);
  __syncthreads();
  if ((threadIdx.x & 63) == 0) sh[threadIdx.x >> 6] = v;
  __syncthreads();
  return sh[0] + sh[1] + sh[2] + sh[3];
}

__global__ __launch_bounds__(256) void softmax_mix_kernel(
    const ushort_t* __restrict__ dotsb, float* __restrict__ out,
    const float* __restrict__ mask_src, const float* __restrict__ steps,
    const float* __restrict__ gates, const float* __restrict__ cv)
{
  __shared__ float sh[4];
  int blk = blockIdx.x;
  int b = blk >> 10, t = blk & 1023;
  int tid = threadIdx.x;
  int s0 = tid * 4;
  float c = steps[b] * (float)t;

  ushort4 dv = *(const ushort4*)(dotsb + (size_t)blk*SS + s0);
  float4 mv = *(const float4*)(mask_src + (size_t)b*SS + s0);
  float4 cva = *(const float4*)(cv + (size_t)b*SS + s0);
  float dvf[4] = {b2f(dv.x) + cva.x, b2f(dv.y) + cva.y, b2f(dv.z) + cva.z, b2f(dv.w) + cva.w};
  float msk[4] = {mv.x, mv.y, mv.z, mv.w};
  float dl[4], ll[4];
  float dmax = -3e38f, lmax = -3e38f;
  #pragma unroll
  for (int r = 0; r < 4; r++){
    float im = INF_ * (1.0f - msk[r]);
    dl[r] = (dvf[r] - im) * (1.0f/32.0f);          // scale = sqrt(1024) = 32
    float dd = (float)(s0 + r) - c;
    ll[r] = -dd*dd*(1.0f/0.3f) - im;
    dmax = fmaxf(dmax, dl[r]);
    lmax = fmaxf(lmax, ll[r]);
  }
  float dm = blkmax(dmax, sh);
  float ps[4], lp[4];
  float psum = 0.f, lsum = 0.f;
  #pragma unroll
  for (int r = 0; r < 4; r++){ ps[r] = __expf(dl[r] - dm); psum += ps[r]; }
  psum = blksum(psum, sh);
  float lm2 = blkmax(lmax, sh);
  #pragma unroll
  for (int r = 0; r < 4; r++){ lp[r] = __expf(ll[r] - lm2); lsum += lp[r]; }
  lsum = blksum(lsum, sh);

  float g = gates[blk];
  float ip = (1.0f - g) / psum, il = g / lsum;
  float4 ov;
  ov.x = ps[0]*ip + lp[0]*il;
  ov.y = ps[1]*ip + lp[1]*il;
  ov.z = ps[2]*ip + lp[2]*il;
  ov.w = ps[3]*ip + lp[3]*il;
  *(float4*)(out + (size_t)blk*SS + s0) = ov;
}

extern "C" void kernel_launch(void* const* d_in, const int* in_sizes, int n_in,
                              void* d_out, int out_size, void* d_ws, size_t ws_size,
                              hipStream_t stream)
{
  const float* key      = (const float*)d_in[0];
  const float* mask_src = (const float*)d_in[1];
  const float* mask_trg = (const float*)d_in[2];
  const float* Wq       = (const float*)d_in[3];
  const float* bq       = (const float*)d_in[4];
  const float* Wk       = (const float*)d_in[5];
  const float* bk       = (const float*)d_in[6];
  const float* wg       = (const float*)d_in[7];
  const float* bg       = (const float*)d_in[8];
  float* out = (float*)d_out;   // fp32 [B,T,S] = 32 MB, written ONLY by softmax
  (void)bk;  // bk contributes only a row-constant softmax shift -> cancels

  // ws layout (~54.3 MB):
  char* ws = (char*)d_ws;
  float* steps     = (float*)ws;                         // 32 B
  float* gates     = (float*)(ws + 4096);                // 32 KB
  float* cv        = (float*)(ws + 4096 + 32768);        // 32 KB
  float* kw        = (float*)(ws + 4096 + 65536);        // 32 KB
  float* v2        = (float*)(ws + 4096 + 98304);        // 4 KB
  ushort_t* WqTb   = (ushort_t*)(ws + 131072);           // 2 MB
  ushort_t* WkTb   = WqTb + (size_t)DD*DD;               // 2 MB
  ushort_t* WmTb   = WkTb + (size_t)DD*DD;               // 2 MB
  ushort_t* keyb   = WmTb + (size_t)DD*DD;               // 16 MB
  ushort_t* kmb    = keyb + (size_t)BB*SS*DD;            // 16 MB (km; DEAD after band -> reused as dotsb)
  char* shared16   = (char*)(kmb + (size_t)BB*SS*DD);    // 16 MB: WmT partials, later qm2b
  float* wmPart    = (float*)shared16;                   // 4 x 1M fp32
  ushort_t* qm2b   = (ushort_t*)shared16;                // 16 MB (after wmt_reduce)
  ushort_t* dotsb  = kmb;                                // bf16 dots in km's dead slot

  pre_kernel<<<2056, 256, 0, stream>>>(Wq, Wk, WqTb, WkTb, mask_src, mask_trg, steps, v2);
  v2_kernel<<<32, 256, 0, stream>>>(Wk, bq, v2);
  key_convert_kernel<<<BB*SS, 256, 0, stream>>>(key, wg, v2, keyb, kw, cv);
  // WmT[f,e] = sum_d Wk[d,f] Wq[d,e] = WkT @ WqT^T, split-K=4 over d
  gemm_bt_kernel<<<256, 256, 0, stream>>>(
      WkTb, WqTb, nullptr, (void*)wmPart, DD, DD, DD/4, DD, DD,
      DD/4, DD/4, (long long)DD*DD, 0, 0, 8, 64);
  wmt_reduce_kernel<<<DD*DD/4/256, 256, 0, stream>>>(wmPart, WmTb);
  // km = keyb @ Wm = gemm_bt(keyb, WmT)  [8192 x 1024 x 1024] -> bf16
  gemm_bt_kernel<<<512, 256, 0, stream>>>(
      keyb, WmTb, nullptr, (void*)kmb, BB*SS, DD, DD, DD, DD, 0, 0, 0, 0, 1, 8, 512);
  // qm2 = l_att · km (banded) + gates
  band_kernel<<<BB*TT/8, 256, 0, stream>>>(kmb, mask_src, steps, kw, bg, qm2b, gates);
  // dots[b] = qm2[b] @ keyb[b]^T -> dotsb (bf16, km's dead slot)
  gemm_bt_kernel<<<512, 256, 0, stream>>>(
      qm2b, keyb, nullptr, (void*)dotsb, TT, SS, DD, DD, DD,
      (long long)TT*DD, (long long)SS*DD, (long long)TT*SS, 0, 1, 8, 64);
  softmax_mix_kernel<<<BB*TT, 256, 0, stream>>>(dotsb, out, mask_src, steps, gates, cv);
}